// Round 3
// baseline (82.657 us; speedup 1.0000x reference)
//
#include <hip/hip_runtime.h>

#define B_N 32768
#define H_N 768
#define L_N 10
#define KB_N 4                  // K-blocks (768 -> 4 x 192)
#define KPB 192                 // K per block
#define KPW 48                  // K per wave (4 waves/block)

// ---------------- Kernel A: partial grouped-GEMM -> d_ws[kb][B][10] --------
__global__ __launch_bounds__(256, 8) void gemm_part(
    const float* __restrict__ hs,
    const float* __restrict__ w1, const float* __restrict__ w2,
    const float* __restrict__ w3,
    const int* __restrict__ groups,
    float* __restrict__ part_out)           // [KB_N][B_N][L_N]
{
    __shared__ float part[4][64][L_N];      // 10,240 B

    const int t    = threadIdx.x;
    const int lane = t & 63;
    const int w    = __builtin_amdgcn_readfirstlane(t >> 6); // wave id
    const int kb   = blockIdx.x & (KB_N - 1);
    const int sg   = blockIdx.x >> 2;       // sample group (64 samples)
    const int s    = sg * 64 + lane;
    const int k0   = kb * KPB + w * KPW;

    const float* hrow = hs + (size_t)s * H_N + k0;
    const float* wp1  = w1 + k0;            // SGPR-based (scalarized)
    const float* wp2  = w2 + k0;
    const float* wp3  = w3 + k0;

    float acc0[L_N], acc1[L_N], acc2[L_N];
    #pragma unroll
    for (int l = 0; l < L_N; ++l) { acc0[l] = 0.f; acc1[l] = 0.f; acc2[l] = 0.f; }

    #pragma unroll 2
    for (int k = 0; k < KPW; k += 4) {
        const float4 h4 = *reinterpret_cast<const float4*>(hrow + k);
        #pragma unroll
        for (int l = 0; l < L_N; ++l) {
            const float4 a = *reinterpret_cast<const float4*>(wp1 + l * H_N + k);
            const float4 b = *reinterpret_cast<const float4*>(wp2 + l * H_N + k);
            const float4 c = *reinterpret_cast<const float4*>(wp3 + l * H_N + k);
            acc0[l] += h4.x * a.x + h4.y * a.y + h4.z * a.z + h4.w * a.w;
            acc1[l] += h4.x * b.x + h4.y * b.y + h4.z * b.z + h4.w * b.w;
            acc2[l] += h4.x * c.x + h4.y * c.y + h4.z * c.z + h4.w * c.w;
        }
    }

    const int g = groups[s];
    #pragma unroll
    for (int l = 0; l < L_N; ++l) {
        float v = (g == 0) ? acc0[l] : ((g == 1) ? acc1[l] : acc2[l]);
        part[w][lane][l] = v;
    }
    __syncthreads();

    if (t < 64) {
        float* dst = part_out + ((size_t)kb * B_N + sg * 64 + t) * L_N;
        #pragma unroll
        for (int l = 0; l < L_N; l += 2) {
            float2 v;
            v.x = part[0][t][l]   + part[1][t][l]   + part[2][t][l]   + part[3][t][l];
            v.y = part[0][t][l+1] + part[1][t][l+1] + part[2][t][l+1] + part[3][t][l+1];
            *reinterpret_cast<float2*>(dst + l) = v;   // 8B-aligned (10*4B stride)
        }
    }
}

// ---------------- Kernel B: combine + bias + CE + mean-reduce --------------
__global__ __launch_bounds__(128) void ce_final(
    const float* __restrict__ part_out,
    const float* __restrict__ b1v, const float* __restrict__ b2v,
    const float* __restrict__ b3v,
    const int* __restrict__ groups, const int* __restrict__ labels,
    float* __restrict__ out)
{
    __shared__ float wsum[2];
    const int t = threadIdx.x;
    const int s = blockIdx.x * 128 + t;

    const int g = groups[s];
    const float* bp = (g == 0) ? b1v : ((g == 1) ? b2v : b3v);

    float logit[L_N];
    #pragma unroll
    for (int l = 0; l < L_N; ++l) logit[l] = bp[l];
    #pragma unroll
    for (int kb = 0; kb < KB_N; ++kb) {
        const float2* p = reinterpret_cast<const float2*>(
            part_out + ((size_t)kb * B_N + s) * L_N);
        #pragma unroll
        for (int l = 0; l < L_N / 2; ++l) {
            float2 v = p[l];
            logit[2*l]   += v.x;
            logit[2*l+1] += v.y;
        }
    }

    float m = logit[0];
    #pragma unroll
    for (int l = 1; l < L_N; ++l) m = fmaxf(m, logit[l]);
    float sum = 0.f;
    #pragma unroll
    for (int l = 0; l < L_N; ++l) sum += expf(logit[l] - m);
    const int lab = labels[s];
    float sel = logit[0];
    #pragma unroll
    for (int l = 1; l < L_N; ++l) sel = (lab == l) ? logit[l] : sel;
    float nll = (m + logf(sum)) - sel;

    #pragma unroll
    for (int off = 32; off > 0; off >>= 1)
        nll += __shfl_down(nll, off, 64);
    if ((t & 63) == 0) wsum[t >> 6] = nll;
    __syncthreads();
    if (t == 0) atomicAdd(out, (wsum[0] + wsum[1]) * (1.0f / (float)B_N));
}

// ---------------- Fallback: R2 single-kernel (if ws too small) -------------
#define SPB 64
#define NCHUNK 8
#define CH (H_N / NCHUNK)

__global__ __launch_bounds__(512, 4) void ce_fused(
    const float* __restrict__ hs,
    const float* __restrict__ w1, const float* __restrict__ b1v,
    const float* __restrict__ w2, const float* __restrict__ b2v,
    const float* __restrict__ w3, const float* __restrict__ b3v,
    const int* __restrict__ groups, const int* __restrict__ labels,
    float* __restrict__ out)
{
    __shared__ float part[NCHUNK][SPB][L_N];
    const int t    = threadIdx.x;
    const int lane = t & 63;
    const int chunk = __builtin_amdgcn_readfirstlane(t >> 6);
    const int s     = blockIdx.x * SPB + lane;

    const float* hrow = hs + (size_t)s * H_N + chunk * CH;
    const float* wp1  = w1 + chunk * CH;
    const float* wp2  = w2 + chunk * CH;
    const float* wp3  = w3 + chunk * CH;

    float acc0[L_N], acc1[L_N], acc2[L_N];
    #pragma unroll
    for (int l = 0; l < L_N; ++l) { acc0[l] = 0.f; acc1[l] = 0.f; acc2[l] = 0.f; }

    #pragma unroll 2
    for (int k = 0; k < CH; k += 4) {
        const float4 h4 = *reinterpret_cast<const float4*>(hrow + k);
        #pragma unroll
        for (int l = 0; l < L_N; ++l) {
            const float4 a = *reinterpret_cast<const float4*>(wp1 + l * H_N + k);
            const float4 b = *reinterpret_cast<const float4*>(wp2 + l * H_N + k);
            const float4 c = *reinterpret_cast<const float4*>(wp3 + l * H_N + k);
            acc0[l] += h4.x * a.x + h4.y * a.y + h4.z * a.z + h4.w * a.w;
            acc1[l] += h4.x * b.x + h4.y * b.y + h4.z * b.z + h4.w * b.w;
            acc2[l] += h4.x * c.x + h4.y * c.y + h4.z * c.z + h4.w * c.w;
        }
    }

    const int g = groups[s];
    #pragma unroll
    for (int l = 0; l < L_N; ++l) {
        float v = (g == 0) ? acc0[l] : ((g == 1) ? acc1[l] : acc2[l]);
        part[chunk][lane][l] = v;
    }
    __syncthreads();

    float nll = 0.f;
    if (t < SPB) {
        const int gg = groups[s];
        const float* bp = (gg == 0) ? b1v : ((gg == 1) ? b2v : b3v);
        float logit[L_N];
        #pragma unroll
        for (int l = 0; l < L_N; ++l) {
            float v = bp[l];
            #pragma unroll
            for (int c = 0; c < NCHUNK; ++c) v += part[c][t][l];
            logit[l] = v;
        }
        float m = logit[0];
        #pragma unroll
        for (int l = 1; l < L_N; ++l) m = fmaxf(m, logit[l]);
        float sum = 0.f;
        #pragma unroll
        for (int l = 0; l < L_N; ++l) sum += expf(logit[l] - m);
        const int lab = labels[s];
        float sel = logit[0];
        #pragma unroll
        for (int l = 1; l < L_N; ++l) sel = (lab == l) ? logit[l] : sel;
        nll = (m + logf(sum)) - sel;
    }
    if (t < 64) {
        #pragma unroll
        for (int off = 32; off > 0; off >>= 1)
            nll += __shfl_down(nll, off, 64);
        if (t == 0) atomicAdd(out, nll * (1.0f / (float)B_N));
    }
}

extern "C" void kernel_launch(void* const* d_in, const int* in_sizes, int n_in,
                              void* d_out, int out_size, void* d_ws, size_t ws_size,
                              hipStream_t stream) {
    const float* hs  = (const float*)d_in[0];
    const float* w1  = (const float*)d_in[1];
    const float* b1v = (const float*)d_in[2];
    const float* w2  = (const float*)d_in[3];
    const float* b2v = (const float*)d_in[4];
    const float* w3  = (const float*)d_in[5];
    const float* b3v = (const float*)d_in[6];
    const int* groups = (const int*)d_in[7];
    const int* labels = (const int*)d_in[8];
    float* out = (float*)d_out;

    hipMemsetAsync(out, 0, sizeof(float), stream);

    const size_t ws_needed = (size_t)KB_N * B_N * L_N * sizeof(float); // 5.24 MB
    if (ws_size >= ws_needed) {
        float* part_out = (float*)d_ws;
        gemm_part<<<(B_N / 64) * KB_N, 256, 0, stream>>>(
            hs, w1, w2, w3, groups, part_out);
        ce_final<<<B_N / 128, 128, 0, stream>>>(
            part_out, b1v, b2v, b3v, groups, labels, out);
    } else {
        ce_fused<<<B_N / SPB, 512, 0, stream>>>(hs, w1, b1v, w2, b2v, w3, b3v,
                                                groups, labels, out);
    }
}

// Round 4
// 68.918 us; speedup vs baseline: 1.1993x; 1.1993x over previous
//
#include <hip/hip_runtime.h>

#define B_N 32768
#define H_N 768
#define L_N 10
#define NW_N 30                 // 3 heads x 10 rows
#define KB_N 4                  // K-blocks (768 -> 4 x 192)
#define KPB 192                 // K per block
#define KPW 48                  // K per wave (4 waves/block)

// ---------------- Kernel A: partial grouped-GEMM -> d_ws[kb][B][10] --------
// Weights staged in LDS (23 KB); inner loop = 1 vmem + 30 uniform ds_read
// + 120 v_fmac per 4 k-elements.
__global__ __launch_bounds__(256, 4) void gemm_part(
    const float* __restrict__ hs,
    const float* __restrict__ w1, const float* __restrict__ w2,
    const float* __restrict__ w3,
    const int* __restrict__ groups,
    float* __restrict__ part_out)           // [KB_N][B_N][L_N]
{
    __shared__ __align__(16) unsigned char lds_raw[NW_N * KPB * 4]; // 23040 B
    float* wlds = (float*)lds_raw;                    // [30][KPB]

    const int t    = threadIdx.x;
    const int lane = t & 63;
    const int w    = __builtin_amdgcn_readfirstlane(t >> 6); // wave id 0..3
    const int kb   = blockIdx.x & (KB_N - 1);
    const int sg   = blockIdx.x >> 2;       // sample group (64 samples)
    const int s    = sg * 64 + lane;

    // ---- stage weight slab [30][KPB] into LDS (coalesced float4) ----
    #pragma unroll
    for (int i = t; i < NW_N * (KPB / 4); i += 256) {
        const int row = i / (KPB / 4);      // 0..29
        const int c4  = i % (KPB / 4);      // 0..47
        const float* src = (row < 10) ? (w1 + row * H_N)
                         : (row < 20) ? (w2 + (row - 10) * H_N)
                                      : (w3 + (row - 20) * H_N);
        const float4 v = *reinterpret_cast<const float4*>(src + kb * KPB + c4 * 4);
        *reinterpret_cast<float4*>(wlds + row * KPB + c4 * 4) = v;
    }
    __syncthreads();

    const float* hrow = hs + (size_t)s * H_N + kb * KPB + w * KPW;
    const int wk = w * KPW;

    float acc0[L_N], acc1[L_N], acc2[L_N];
    #pragma unroll
    for (int l = 0; l < L_N; ++l) { acc0[l] = 0.f; acc1[l] = 0.f; acc2[l] = 0.f; }

    #pragma unroll 2
    for (int k = 0; k < KPW; k += 4) {
        const float4 h4 = *reinterpret_cast<const float4*>(hrow + k);
        #pragma unroll
        for (int l = 0; l < L_N; ++l) {
            const float4 a = *reinterpret_cast<const float4*>(wlds + l * KPB + wk + k);
            const float4 b = *reinterpret_cast<const float4*>(wlds + (l + 10) * KPB + wk + k);
            const float4 c = *reinterpret_cast<const float4*>(wlds + (l + 20) * KPB + wk + k);
            acc0[l] = fmaf(h4.x, a.x, acc0[l]); acc0[l] = fmaf(h4.y, a.y, acc0[l]);
            acc0[l] = fmaf(h4.z, a.z, acc0[l]); acc0[l] = fmaf(h4.w, a.w, acc0[l]);
            acc1[l] = fmaf(h4.x, b.x, acc1[l]); acc1[l] = fmaf(h4.y, b.y, acc1[l]);
            acc1[l] = fmaf(h4.z, b.z, acc1[l]); acc1[l] = fmaf(h4.w, b.w, acc1[l]);
            acc2[l] = fmaf(h4.x, c.x, acc2[l]); acc2[l] = fmaf(h4.y, c.y, acc2[l]);
            acc2[l] = fmaf(h4.z, c.z, acc2[l]); acc2[l] = fmaf(h4.w, c.w, acc2[l]);
        }
    }

    // All waves done reading weights before we overwrite the LDS.
    __syncthreads();
    float (*part)[64][L_N] = (float (*)[64][L_N])lds_raw;   // 10240 B

    const int g = groups[s];
    #pragma unroll
    for (int l = 0; l < L_N; ++l) {
        float v = (g == 0) ? acc0[l] : ((g == 1) ? acc1[l] : acc2[l]);
        part[w][lane][l] = v;
    }
    __syncthreads();

    if (t < 64) {
        float* dst = part_out + ((size_t)kb * B_N + sg * 64 + t) * L_N;
        #pragma unroll
        for (int l = 0; l < L_N; l += 2) {
            float2 v;
            v.x = part[0][t][l]   + part[1][t][l]   + part[2][t][l]   + part[3][t][l];
            v.y = part[0][t][l+1] + part[1][t][l+1] + part[2][t][l+1] + part[3][t][l+1];
            *reinterpret_cast<float2*>(dst + l) = v;
        }
    }
}

// ---------------- Kernel B: combine + bias + CE + mean-reduce --------------
__global__ __launch_bounds__(128) void ce_final(
    const float* __restrict__ part_out,
    const float* __restrict__ b1v, const float* __restrict__ b2v,
    const float* __restrict__ b3v,
    const int* __restrict__ groups, const int* __restrict__ labels,
    float* __restrict__ out)
{
    __shared__ float wsum[2];
    const int t = threadIdx.x;
    const int s = blockIdx.x * 128 + t;

    const int g = groups[s];
    const float* bp = (g == 0) ? b1v : ((g == 1) ? b2v : b3v);

    float logit[L_N];
    #pragma unroll
    for (int l = 0; l < L_N; ++l) logit[l] = bp[l];
    #pragma unroll
    for (int kb = 0; kb < KB_N; ++kb) {
        const float2* p = reinterpret_cast<const float2*>(
            part_out + ((size_t)kb * B_N + s) * L_N);
        #pragma unroll
        for (int l = 0; l < L_N / 2; ++l) {
            float2 v = p[l];
            logit[2*l]   += v.x;
            logit[2*l+1] += v.y;
        }
    }

    float m = logit[0];
    #pragma unroll
    for (int l = 1; l < L_N; ++l) m = fmaxf(m, logit[l]);
    float sum = 0.f;
    #pragma unroll
    for (int l = 0; l < L_N; ++l) sum += expf(logit[l] - m);
    const int lab = labels[s];
    float sel = logit[0];
    #pragma unroll
    for (int l = 1; l < L_N; ++l) sel = (lab == l) ? logit[l] : sel;
    float nll = (m + logf(sum)) - sel;

    #pragma unroll
    for (int off = 32; off > 0; off >>= 1)
        nll += __shfl_down(nll, off, 64);
    if ((t & 63) == 0) wsum[t >> 6] = nll;
    __syncthreads();
    if (t == 0) atomicAdd(out, (wsum[0] + wsum[1]) * (1.0f / (float)B_N));
}

// ---------------- Fallback: single-kernel (if ws too small) ----------------
#define SPB 64
#define NCHUNK 8
#define CH (H_N / NCHUNK)

__global__ __launch_bounds__(512, 4) void ce_fused(
    const float* __restrict__ hs,
    const float* __restrict__ w1, const float* __restrict__ b1v,
    const float* __restrict__ w2, const float* __restrict__ b2v,
    const float* __restrict__ w3, const float* __restrict__ b3v,
    const int* __restrict__ groups, const int* __restrict__ labels,
    float* __restrict__ out)
{
    __shared__ float part[NCHUNK][SPB][L_N];
    const int t    = threadIdx.x;
    const int lane = t & 63;
    const int chunk = __builtin_amdgcn_readfirstlane(t >> 6);
    const int s     = blockIdx.x * SPB + lane;

    const float* hrow = hs + (size_t)s * H_N + chunk * CH;
    const float* wp1  = w1 + chunk * CH;
    const float* wp2  = w2 + chunk * CH;
    const float* wp3  = w3 + chunk * CH;

    float acc0[L_N], acc1[L_N], acc2[L_N];
    #pragma unroll
    for (int l = 0; l < L_N; ++l) { acc0[l] = 0.f; acc1[l] = 0.f; acc2[l] = 0.f; }

    #pragma unroll 2
    for (int k = 0; k < CH; k += 4) {
        const float4 h4 = *reinterpret_cast<const float4*>(hrow + k);
        #pragma unroll
        for (int l = 0; l < L_N; ++l) {
            const float4 a = *reinterpret_cast<const float4*>(wp1 + l * H_N + k);
            const float4 b = *reinterpret_cast<const float4*>(wp2 + l * H_N + k);
            const float4 c = *reinterpret_cast<const float4*>(wp3 + l * H_N + k);
            acc0[l] += h4.x * a.x + h4.y * a.y + h4.z * a.z + h4.w * a.w;
            acc1[l] += h4.x * b.x + h4.y * b.y + h4.z * b.z + h4.w * b.w;
            acc2[l] += h4.x * c.x + h4.y * c.y + h4.z * c.z + h4.w * c.w;
        }
    }

    const int g = groups[s];
    #pragma unroll
    for (int l = 0; l < L_N; ++l) {
        float v = (g == 0) ? acc0[l] : ((g == 1) ? acc1[l] : acc2[l]);
        part[chunk][lane][l] = v;
    }
    __syncthreads();

    float nll = 0.f;
    if (t < SPB) {
        const int gg = groups[s];
        const float* bp = (gg == 0) ? b1v : ((gg == 1) ? b2v : b3v);
        float logit[L_N];
        #pragma unroll
        for (int l = 0; l < L_N; ++l) {
            float v = bp[l];
            #pragma unroll
            for (int c = 0; c < NCHUNK; ++c) v += part[c][t][l];
            logit[l] = v;
        }
        float m = logit[0];
        #pragma unroll
        for (int l = 1; l < L_N; ++l) m = fmaxf(m, logit[l]);
        float sum = 0.f;
        #pragma unroll
        for (int l = 0; l < L_N; ++l) sum += expf(logit[l] - m);
        const int lab = labels[s];
        float sel = logit[0];
        #pragma unroll
        for (int l = 1; l < L_N; ++l) sel = (lab == l) ? logit[l] : sel;
        nll = (m + logf(sum)) - sel;
    }
    if (t < 64) {
        #pragma unroll
        for (int off = 32; off > 0; off >>= 1)
            nll += __shfl_down(nll, off, 64);
        if (t == 0) atomicAdd(out, nll * (1.0f / (float)B_N));
    }
}

extern "C" void kernel_launch(void* const* d_in, const int* in_sizes, int n_in,
                              void* d_out, int out_size, void* d_ws, size_t ws_size,
                              hipStream_t stream) {
    const float* hs  = (const float*)d_in[0];
    const float* w1  = (const float*)d_in[1];
    const float* b1v = (const float*)d_in[2];
    const float* w2  = (const float*)d_in[3];
    const float* b2v = (const float*)d_in[4];
    const float* w3  = (const float*)d_in[5];
    const float* b3v = (const float*)d_in[6];
    const int* groups = (const int*)d_in[7];
    const int* labels = (const int*)d_in[8];
    float* out = (float*)d_out;

    hipMemsetAsync(out, 0, sizeof(float), stream);

    const size_t ws_needed = (size_t)KB_N * B_N * L_N * sizeof(float); // 5.24 MB
    if (ws_size >= ws_needed) {
        float* part_out = (float*)d_ws;
        gemm_part<<<(B_N / 64) * KB_N, 256, 0, stream>>>(
            hs, w1, w2, w3, groups, part_out);
        ce_final<<<B_N / 128, 128, 0, stream>>>(
            part_out, b1v, b2v, b3v, groups, labels, out);
    } else {
        ce_fused<<<B_N / SPB, 512, 0, stream>>>(hs, w1, b1v, w2, b2v, w3, b3v,
                                                groups, labels, out);
    }
}